// Round 6
// baseline (263.551 us; speedup 1.0000x reference)
//
#include <hip/hip_runtime.h>
#include <math.h>

// MS-SSIM on (16,1,512,512) fp32, 5 levels, 11x11 gaussian (sigma=1.5), 2x2 avg-pool.
// Round-5 structure: ONE kernel (2736 blocks) + 4-byte memset.
//   - Every block is self-sufficient: level-l blocks (l>=1) pool their own
//     42x80 input region straight from the original image via the exact
//     0.25*((a+b)+(c+d)) quad-tree (bit-identical to reference pooling),
//     into LDS pS/pD; then the proven 64x32 SSIM tile (s/d 4-plane separable
//     conv) runs with LDS-sourced phase H.
//   - Deep levels dispatched FIRST (lin 0..687) so their pooling latency
//     hides under the 2048-block L0 stream.
//   - L0 phase H: interior fast path (no boundary masks for 65% of blocks).
//   - Finalize fused: device-scope atomic counter; last block reduces all
//     partials, applies weights, clips, writes the scalar.

#define WS 11
#define TW 64
#define TH 32
#define SROWS 42      // TH + 10 h-rows per tile
#define HSTRIDE 68    // h-plane row stride
#define PSTRIDE 84    // pooled-staging row stride
#define NBLK 2736

__device__ __forceinline__ void gauss_weights(float* w) {
    float s = 0.f;
#pragma unroll
    for (int j = 0; j < WS; ++j) {
        float d = (float)(j - 5);
        float e = expf(-d * d / 4.5f);   // 2*sigma^2 = 4.5
        w[j] = e;
        s += e;
    }
    float inv = 1.f / s;
#pragma unroll
    for (int j = 0; j < WS; ++j) w[j] *= inv;
}

// Exact reference pooling tree: P_L(y,x) = 0.25*((P_{L-1}(2y,2x)+P_{L-1}(2y,2x+1))
//                                             + (P_{L-1}(2y+1,2x)+P_{L-1}(2y+1,2x+1)))
template<int L>
__device__ __forceinline__ float poolT(const float* __restrict__ img, int y, int x) {
    if constexpr (L == 0) {
        return img[(y << 9) + x];
    } else {
        return 0.25f * ((poolT<L-1>(img, 2*y, 2*x)   + poolT<L-1>(img, 2*y, 2*x+1)) +
                        (poolT<L-1>(img, 2*y+1, 2*x) + poolT<L-1>(img, 2*y+1, 2*x+1)));
    }
}

__global__ __launch_bounds__(256) void msssim_all_kernel(
    const float* __restrict__ img1, const float* __restrict__ img2,
    float* __restrict__ partials, unsigned int* __restrict__ counter,
    float* __restrict__ out)
{
    __shared__ float hS[SROWS * HSTRIDE];
    __shared__ float hD[SROWS * HSTRIDE];
    __shared__ float hS2[SROWS * HSTRIDE];
    __shared__ float hD2[SROWS * HSTRIDE];
    __shared__ float pS[SROWS * PSTRIDE];
    __shared__ float pD[SROWS * PSTRIDE];
    __shared__ float red[2][4];
    __shared__ int lastflag;

    const int tid = threadIdx.x;
    const int lin = blockIdx.x;

    // ---- level decode: deep levels first.
    int level, li;
    if (lin < 16)       { level = 4; li = lin; }
    else if (lin < 48)  { level = 3; li = lin - 16; }
    else if (lin < 176) { level = 2; li = lin - 48; }
    else if (lin < 688) { level = 1; li = lin - 176; }
    else                { level = 0; li = lin - 688; }

    const int ntxl[5] = {3, 2, 1, 0, 0};
    const int ntyl[5] = {4, 3, 2, 1, 0};
    const int W = 512 >> level;
    const int tx = li & ((1 << ntxl[level]) - 1);
    const int rem = li >> ntxl[level];
    const int ty = rem & ((1 << ntyl[level]) - 1);
    const int b = rem >> ntyl[level];
    const int x0 = tx * TW, y0 = ty * TH;

    const float* p1 = img1 + (size_t)b * 512 * 512;
    const float* p2 = img2 + (size_t)b * 512 * 512;

    float w[WS];
    gauss_weights(w);

    // ---- Phase P (l>=1): pool this tile's 42x80 input region into LDS.
    if (level > 0) {
        if (level == 1) {
            for (int t = tid; t < SROWS * 80; t += 256) {
                int r = t / 80, c = t - r * 80;
                int gy = y0 - 5 + r, gx = x0 - 8 + c;
                float vS = 0.f, vD = 0.f;
                if ((unsigned)gy < (unsigned)W && (unsigned)gx < (unsigned)W) {
                    float a = poolT<1>(p1, gy, gx);
                    float bb = poolT<1>(p2, gy, gx);
                    vS = a + bb; vD = a - bb;
                }
                pS[r * PSTRIDE + c] = vS;
                pD[r * PSTRIDE + c] = vD;
            }
        } else if (level == 2) {
            for (int t = tid; t < SROWS * 80; t += 256) {
                int r = t / 80, c = t - r * 80;
                int gy = y0 - 5 + r, gx = x0 - 8 + c;
                float vS = 0.f, vD = 0.f;
                if ((unsigned)gy < (unsigned)W && (unsigned)gx < (unsigned)W) {
                    float a = poolT<2>(p1, gy, gx);
                    float bb = poolT<2>(p2, gy, gx);
                    vS = a + bb; vD = a - bb;
                }
                pS[r * PSTRIDE + c] = vS;
                pD[r * PSTRIDE + c] = vD;
            }
        } else if (level == 3) {
            for (int t = tid; t < SROWS * 80; t += 256) {
                int r = t / 80, c = t - r * 80;
                int gy = y0 - 5 + r, gx = x0 - 8 + c;
                float vS = 0.f, vD = 0.f;
                if ((unsigned)gy < (unsigned)W && (unsigned)gx < (unsigned)W) {
                    float a = poolT<3>(p1, gy, gx);
                    float bb = poolT<3>(p2, gy, gx);
                    vS = a + bb; vD = a - bb;
                }
                pS[r * PSTRIDE + c] = vS;
                pD[r * PSTRIDE + c] = vD;
            }
        } else {
            for (int t = tid; t < SROWS * 80; t += 256) {
                int r = t / 80, c = t - r * 80;
                int gy = y0 - 5 + r, gx = x0 - 8 + c;
                float vS = 0.f, vD = 0.f;
                if ((unsigned)gy < (unsigned)W && (unsigned)gx < (unsigned)W) {
                    float a = poolT<4>(p1, gy, gx);
                    float bb = poolT<4>(p2, gy, gx);
                    vS = a + bb; vD = a - bb;
                }
                pS[r * PSTRIDE + c] = vS;
                pD[r * PSTRIDE + c] = vD;
            }
        }
        __syncthreads();
    }

    // ---- Phase H: horizontal 11-tap conv of s, d, s^2, d^2 into h-planes.
    const bool interior = (level == 0) && (x0 >= 8) && (x0 <= 440) &&
                          (y0 >= 5) && (y0 <= 475);
#pragma unroll 1
    for (int t = tid; t < SROWS * 16; t += 256) {
        int r = t >> 4, xg = t & 15;
        float fs[20], fd[20];
        if (level == 0) {
            int gy = y0 - 5 + r;
            int gxb = x0 - 8 + 4 * xg;
            if (interior) {
                const float* r1p = p1 + (size_t)gy * 512 + gxb;
                const float* r2p = p2 + (size_t)gy * 512 + gxb;
#pragma unroll
                for (int k = 0; k < 5; ++k) {
                    float4 a = *(const float4*)(r1p + 4 * k);
                    float4 c = *(const float4*)(r2p + 4 * k);
                    fs[4 * k]     = a.x + c.x;  fd[4 * k]     = a.x - c.x;
                    fs[4 * k + 1] = a.y + c.y;  fd[4 * k + 1] = a.y - c.y;
                    fs[4 * k + 2] = a.z + c.z;  fd[4 * k + 2] = a.z - c.z;
                    fs[4 * k + 3] = a.w + c.w;  fd[4 * k + 3] = a.w - c.w;
                }
            } else if (gy >= 0 && gy < 512) {
                const float* r1p = p1 + (size_t)gy * 512;
                const float* r2p = p2 + (size_t)gy * 512;
#pragma unroll
                for (int k = 0; k < 5; ++k) {
                    int gx = gxb + 4 * k;
                    float4 a = make_float4(0.f, 0.f, 0.f, 0.f);
                    float4 c = make_float4(0.f, 0.f, 0.f, 0.f);
                    if (gx >= 0 && gx + 3 < 512) {
                        a = *(const float4*)(r1p + gx);
                        c = *(const float4*)(r2p + gx);
                    } else if (gx + 3 >= 0 && gx < 512) {
                        float t1[4] = {0.f, 0.f, 0.f, 0.f};
                        float t2[4] = {0.f, 0.f, 0.f, 0.f};
#pragma unroll
                        for (int u = 0; u < 4; ++u) {
                            int gxx = gx + u;
                            if (gxx >= 0 && gxx < 512) { t1[u] = r1p[gxx]; t2[u] = r2p[gxx]; }
                        }
                        a = make_float4(t1[0], t1[1], t1[2], t1[3]);
                        c = make_float4(t2[0], t2[1], t2[2], t2[3]);
                    }
                    fs[4 * k]     = a.x + c.x;  fd[4 * k]     = a.x - c.x;
                    fs[4 * k + 1] = a.y + c.y;  fd[4 * k + 1] = a.y - c.y;
                    fs[4 * k + 2] = a.z + c.z;  fd[4 * k + 2] = a.z - c.z;
                    fs[4 * k + 3] = a.w + c.w;  fd[4 * k + 3] = a.w - c.w;
                }
            } else {
#pragma unroll
                for (int k = 0; k < 20; ++k) { fs[k] = 0.f; fd[k] = 0.f; }
            }
        } else {
            int base = r * PSTRIDE + 4 * xg;
#pragma unroll
            for (int k = 0; k < 5; ++k) {
                float4 a = *(const float4*)&pS[base + 4 * k];
                float4 c = *(const float4*)&pD[base + 4 * k];
                fs[4 * k]     = a.x;  fd[4 * k]     = c.x;
                fs[4 * k + 1] = a.y;  fd[4 * k + 1] = c.y;
                fs[4 * k + 2] = a.z;  fd[4 * k + 2] = c.z;
                fs[4 * k + 3] = a.w;  fd[4 * k + 3] = c.w;
            }
        }
        float qs[14], qd[14];
#pragma unroll
        for (int k = 0; k < 14; ++k) {
            qs[k] = fs[k + 3] * fs[k + 3];
            qd[k] = fd[k + 3] * fd[k + 3];
        }
        float oS[4], oD[4], oS2[4], oD2[4];
#pragma unroll
        for (int c = 0; c < 4; ++c) {
            float aS = 0.f, aD = 0.f, aS2 = 0.f, aD2 = 0.f;
#pragma unroll
            for (int j = 0; j < WS; ++j) {
                float wj = w[j];
                aS  = fmaf(wj, fs[3 + c + j], aS);
                aD  = fmaf(wj, fd[3 + c + j], aD);
                aS2 = fmaf(wj, qs[c + j], aS2);
                aD2 = fmaf(wj, qd[c + j], aD2);
            }
            oS[c] = aS; oD[c] = aD; oS2[c] = aS2; oD2[c] = aD2;
        }
        int ho = r * HSTRIDE + 4 * xg;
        *(float4*)&hS[ho]  = make_float4(oS[0], oS[1], oS[2], oS[3]);
        *(float4*)&hD[ho]  = make_float4(oD[0], oD[1], oD[2], oD[3]);
        *(float4*)&hS2[ho] = make_float4(oS2[0], oS2[1], oS2[2], oS2[3]);
        *(float4*)&hD2[ho] = make_float4(oD2[0], oD2[1], oD2[2], oD2[3]);
    }
    __syncthreads();

    // ---- Phase V: vertical conv + SSIM/MCS via s/d identities.
    const int x = tid & 15;
    const int g = tid >> 4;
    float accS[2][4], accD[2][4], accS2[2][4], accD2[2][4];
#pragma unroll
    for (int rr = 0; rr < 2; ++rr)
#pragma unroll
        for (int c = 0; c < 4; ++c) {
            accS[rr][c] = 0.f; accD[rr][c] = 0.f;
            accS2[rr][c] = 0.f; accD2[rr][c] = 0.f;
        }

#pragma unroll
    for (int r = 0; r < 12; ++r) {
        int ho = (2 * g + r) * HSTRIDE + 4 * x;
        float4 vS  = *(const float4*)&hS[ho];
        float4 vD  = *(const float4*)&hD[ho];
        float4 vS2 = *(const float4*)&hS2[ho];
        float4 vD2 = *(const float4*)&hD2[ho];
        float lS[4] = {vS.x, vS.y, vS.z, vS.w};
        float lD[4] = {vD.x, vD.y, vD.z, vD.w};
        float lS2[4] = {vS2.x, vS2.y, vS2.z, vS2.w};
        float lD2[4] = {vD2.x, vD2.y, vD2.z, vD2.w};
        if (r < 11) {
            float wv = w[r];
#pragma unroll
            for (int c = 0; c < 4; ++c) {
                accS[0][c]  = fmaf(wv, lS[c],  accS[0][c]);
                accD[0][c]  = fmaf(wv, lD[c],  accD[0][c]);
                accS2[0][c] = fmaf(wv, lS2[c], accS2[0][c]);
                accD2[0][c] = fmaf(wv, lD2[c], accD2[0][c]);
            }
        }
        if (r >= 1) {
            float wv = w[r - 1];
#pragma unroll
            for (int c = 0; c < 4; ++c) {
                accS[1][c]  = fmaf(wv, lS[c],  accS[1][c]);
                accD[1][c]  = fmaf(wv, lD[c],  accD[1][c]);
                accS2[1][c] = fmaf(wv, lS2[c], accS2[1][c]);
                accD2[1][c] = fmaf(wv, lD2[c], accD2[1][c]);
            }
        }
    }

    const float C1 = 6.5025f;
    const float C2 = 58.5225f;
    const int Hv = min(TH, W - y0);
    const int Wv = min(TW, W - x0);
    float sacc = 0.f, macc = 0.f;
#pragma unroll
    for (int rr = 0; rr < 2; ++rr) {
        int row = 2 * g + rr;
#pragma unroll
        for (int c = 0; c < 4; ++c) {
            float ms = accS[rr][c], md = accD[rr][c];
            float es = accS2[rr][c], ed = accD2[rr][c];
            float ms2 = ms * ms, md2 = md * md;
            float a  = 0.5f * (ms2 - md2);   // 2*mu1*mu2
            float bb = 0.5f * (ms2 + md2);   // mu1^2 + mu2^2
            float pq = 0.5f * (es - ed);     // 2*E[xy]
            float qq = 0.5f * (es + ed);     // E[x^2]+E[y^2]
            float V1 = (pq - a) + C2;
            float V2 = (qq - bb) + C2;
            float num = a + C1;
            float den = bb + C1;
            float inv = 1.0f / (den * V2);
            float sv = num * V1 * inv;
            float mv = V1 * den * inv;
            if (row < Hv && (4 * x + c) < Wv) { sacc += sv; macc += mv; }
        }
    }

#pragma unroll
    for (int o = 32; o > 0; o >>= 1) {
        sacc += __shfl_down(sacc, o);
        macc += __shfl_down(macc, o);
    }
    int wave = tid >> 6, lane = tid & 63;
    if (lane == 0) { red[0][wave] = sacc; red[1][wave] = macc; }
    __syncthreads();
    if (tid == 0) {
        float s = red[0][0] + red[0][1] + red[0][2] + red[0][3];
        float m = red[1][0] + red[1][1] + red[1][2] + red[1][3];
        partials[2 * lin] = s;
        partials[2 * lin + 1] = m;
        __threadfence();
        unsigned int old = __hip_atomic_fetch_add(counter, 1u, __ATOMIC_ACQ_REL,
                                                  __HIP_MEMORY_SCOPE_AGENT);
        lastflag = (old == NBLK - 1) ? 1 : 0;
    }
    __syncthreads();

    // ---- Last block: fused finalize.
    if (lastflag) {
        __threadfence();
        // k: 0->L4, 1->L3, 2->L2, 3->L1, 4->L0 (partials order)
        const int offk[5] = {0, 16, 48, 176, 688};
        const int endk[5] = {16, 48, 176, 688, NBLK};
        float aS[5], aM[5];
#pragma unroll
        for (int k = 0; k < 5; ++k) {
            float s = 0.f, m = 0.f;
            for (int i = offk[k] + tid; i < endk[k]; i += 256) {
                s += partials[2 * i];
                m += partials[2 * i + 1];
            }
            aS[k] = s; aM[k] = m;
        }
#pragma unroll
        for (int o = 32; o > 0; o >>= 1) {
#pragma unroll
            for (int k = 0; k < 5; ++k) {
                aS[k] += __shfl_down(aS[k], o);
                aM[k] += __shfl_down(aM[k], o);
            }
        }
        if (lane == 0) {
#pragma unroll
            for (int k = 0; k < 5; ++k) {
                pS[wave * 16 + k] = aS[k];
                pS[wave * 16 + 8 + k] = aM[k];
            }
        }
        __syncthreads();
        if (tid == 0) {
            // npix in k order (L4..L0)
            const float npix[5] = {16384.f, 65536.f, 262144.f, 1048576.f, 4194304.f};
            float ls[5], lm[5];
#pragma unroll
            for (int k = 0; k < 5; ++k) {
                float s = pS[k] + pS[16 + k] + pS[32 + k] + pS[48 + k];
                float m = pS[8 + k] + pS[24 + k] + pS[40 + k] + pS[56 + k];
                ls[k] = s / npix[k];
                lm[k] = m / npix[k];
            }
            // level order: L0=k4, L1=k3, L2=k2, L3=k1, L4=k0
            const float wt[5] = {0.0448f, 0.2856f, 0.3001f, 0.2363f, 0.1333f};
            float v = powf(lm[4], wt[0]) * powf(lm[3], wt[1]) * powf(lm[2], wt[2]) *
                      powf(lm[1], wt[3]) * powf(ls[0], wt[4]);
            v *= 0.5f;
            v = fminf(fmaxf(v, 0.f), 1.f);
            out[0] = v;
        }
    }
}

extern "C" void kernel_launch(void* const* d_in, const int* in_sizes, int n_in,
                              void* d_out, int out_size, void* d_ws, size_t ws_size,
                              hipStream_t stream) {
    const float* img1 = (const float*)d_in[0];
    const float* img2 = (const float*)d_in[1];
    float* out = (float*)d_out;

    float* wsf = (float*)d_ws;
    float* partials = wsf;                          // NBLK * 2 floats
    unsigned int* counter = (unsigned int*)(wsf + 2 * NBLK);

    hipMemsetAsync(counter, 0, sizeof(unsigned int), stream);

    msssim_all_kernel<<<dim3(NBLK), dim3(256), 0, stream>>>(
        img1, img2, partials, counter, out);
}

// Round 8
// 254.686 us; speedup vs baseline: 1.0348x; 1.0348x over previous
//
#include <hip/hip_runtime.h>
#include <hip/hip_fp16.h>
#include <math.h>

// MS-SSIM on (16,1,512,512) fp32, 5 levels, 11x11 gaussian (sigma=1.5), 2x2 avg-pool.
// Round-7 = Round-6 resubmitted verbatim (R6 bench was a GPU-acquisition
// timeout; the kernel never ran).
// Structure (3 dispatches):
//   A) ssim_l0_pool_kernel (2048 blocks): L0 SSIM 64x32 tile + exact-fp32 pool
//      pyramid emission (L1 all-threads via LDS pl1; L2..L4 wave0 from pl1).
//   B) ssim_rest_kernel (688 blocks): SSIM levels 1..4 from pooled arrays.
//   C) finalize_kernel.
//   - h-planes stored in LDS as __half2 pairs (S,D) and (S2,D2): LDS 50.7->27.5 KB
//     (occupancy 2-3 -> 4 blocks/CU), phase-V LDS reads halved. SSIM math still
//     fp32; only the intermediate h-conv planes are fp16 (error ~1e-4 << 1e-2).
//   - Phase H as 3 explicit pipelined task calls (no unroll-1 serialization).
//   - __launch_bounds__(256,4) caps VGPR at 128.

#define WS 11
#define TW 64
#define TH 32
#define SROWS 42      // TH + 10 h-rows per tile
#define HSTRIDE 68    // h-plane row stride in __half2 entries (4B each)

__device__ __forceinline__ void gauss_weights(float* w) {
    float s = 0.f;
#pragma unroll
    for (int j = 0; j < WS; ++j) {
        float d = (float)(j - 5);
        float e = expf(-d * d / 4.5f);   // 2*sigma^2 = 4.5
        w[j] = e;
        s += e;
    }
    float inv = 1.f / s;
#pragma unroll
    for (int j = 0; j < WS; ++j) w[j] *= inv;
}

// One horizontal-conv task: h-row r, 4-col group xg (t = r*16+xg).
__device__ __forceinline__ void h_task(
    int t, const float* __restrict__ p1, const float* __restrict__ p2,
    int W, int x0, int y0, bool interior, const float* w,
    __half2* __restrict__ hSD, __half2* __restrict__ hQ)
{
    int r = t >> 4, xg = t & 15;
    int gy = y0 - 5 + r;
    int gxb = x0 - 8 + 4 * xg;
    float fs[20], fd[20];
    if (interior) {
        const float* r1p = p1 + (size_t)gy * W + gxb;
        const float* r2p = p2 + (size_t)gy * W + gxb;
#pragma unroll
        for (int k = 0; k < 5; ++k) {
            float4 a = *(const float4*)(r1p + 4 * k);
            float4 c = *(const float4*)(r2p + 4 * k);
            fs[4 * k]     = a.x + c.x;  fd[4 * k]     = a.x - c.x;
            fs[4 * k + 1] = a.y + c.y;  fd[4 * k + 1] = a.y - c.y;
            fs[4 * k + 2] = a.z + c.z;  fd[4 * k + 2] = a.z - c.z;
            fs[4 * k + 3] = a.w + c.w;  fd[4 * k + 3] = a.w - c.w;
        }
    } else if (gy >= 0 && gy < W) {
        const float* r1p = p1 + (size_t)gy * W;
        const float* r2p = p2 + (size_t)gy * W;
#pragma unroll
        for (int k = 0; k < 5; ++k) {
            int gx = gxb + 4 * k;
            float4 a = make_float4(0.f, 0.f, 0.f, 0.f);
            float4 c = make_float4(0.f, 0.f, 0.f, 0.f);
            if (gx >= 0 && gx + 3 < W) {
                a = *(const float4*)(r1p + gx);
                c = *(const float4*)(r2p + gx);
            } else if (gx + 3 >= 0 && gx < W) {
                float t1[4] = {0.f, 0.f, 0.f, 0.f};
                float t2[4] = {0.f, 0.f, 0.f, 0.f};
#pragma unroll
                for (int u = 0; u < 4; ++u) {
                    int gxx = gx + u;
                    if (gxx >= 0 && gxx < W) { t1[u] = r1p[gxx]; t2[u] = r2p[gxx]; }
                }
                a = make_float4(t1[0], t1[1], t1[2], t1[3]);
                c = make_float4(t2[0], t2[1], t2[2], t2[3]);
            }
            fs[4 * k]     = a.x + c.x;  fd[4 * k]     = a.x - c.x;
            fs[4 * k + 1] = a.y + c.y;  fd[4 * k + 1] = a.y - c.y;
            fs[4 * k + 2] = a.z + c.z;  fd[4 * k + 2] = a.z - c.z;
            fs[4 * k + 3] = a.w + c.w;  fd[4 * k + 3] = a.w - c.w;
        }
    } else {
#pragma unroll
        for (int k = 0; k < 20; ++k) { fs[k] = 0.f; fd[k] = 0.f; }
    }
    float qs[14], qd[14];
#pragma unroll
    for (int k = 0; k < 14; ++k) {
        qs[k] = fs[k + 3] * fs[k + 3];
        qd[k] = fd[k + 3] * fd[k + 3];
    }
    __half2 outSD[4], outQ[4];
#pragma unroll
    for (int c = 0; c < 4; ++c) {
        float aS = 0.f, aD = 0.f, aS2 = 0.f, aD2 = 0.f;
#pragma unroll
        for (int j = 0; j < WS; ++j) {
            float wj = w[j];
            aS  = fmaf(wj, fs[3 + c + j], aS);
            aD  = fmaf(wj, fd[3 + c + j], aD);
            aS2 = fmaf(wj, qs[c + j], aS2);
            aD2 = fmaf(wj, qd[c + j], aD2);
        }
        outSD[c] = __float22half2_rn(make_float2(aS, aD));
        outQ[c]  = __float22half2_rn(make_float2(aS2, aD2));
    }
    int ho = r * HSTRIDE + 4 * xg;
    *(float4*)&hSD[ho] = *(const float4*)outSD;
    *(float4*)&hQ[ho]  = *(const float4*)outQ;
}

// Phase V + SSIM + block reduction; writes partials[part_idx].
__device__ __forceinline__ void v_phase(
    int W, int x0, int y0, const float* w,
    const __half2* __restrict__ hSD, const __half2* __restrict__ hQ,
    float red[2][4], float* __restrict__ partials, int part_idx)
{
    const int tid = threadIdx.x;
    const int x = tid & 15;
    const int g = tid >> 4;
    float accS[2][4], accD[2][4], accS2[2][4], accD2[2][4];
#pragma unroll
    for (int rr = 0; rr < 2; ++rr)
#pragma unroll
        for (int c = 0; c < 4; ++c) {
            accS[rr][c] = 0.f; accD[rr][c] = 0.f;
            accS2[rr][c] = 0.f; accD2[rr][c] = 0.f;
        }

#pragma unroll
    for (int r = 0; r < 12; ++r) {
        int ho = (2 * g + r) * HSTRIDE + 4 * x;
        float4 rawSD = *(const float4*)&hSD[ho];
        float4 rawQ  = *(const float4*)&hQ[ho];
        const __half2* hpSD = (const __half2*)&rawSD;
        const __half2* hpQ  = (const __half2*)&rawQ;
        float lS[4], lD[4], lS2[4], lD2[4];
#pragma unroll
        for (int c = 0; c < 4; ++c) {
            float2 sd = __half22float2(hpSD[c]);
            float2 q  = __half22float2(hpQ[c]);
            lS[c] = sd.x; lD[c] = sd.y; lS2[c] = q.x; lD2[c] = q.y;
        }
        if (r < 11) {
            float wv = w[r];
#pragma unroll
            for (int c = 0; c < 4; ++c) {
                accS[0][c]  = fmaf(wv, lS[c],  accS[0][c]);
                accD[0][c]  = fmaf(wv, lD[c],  accD[0][c]);
                accS2[0][c] = fmaf(wv, lS2[c], accS2[0][c]);
                accD2[0][c] = fmaf(wv, lD2[c], accD2[0][c]);
            }
        }
        if (r >= 1) {
            float wv = w[r - 1];
#pragma unroll
            for (int c = 0; c < 4; ++c) {
                accS[1][c]  = fmaf(wv, lS[c],  accS[1][c]);
                accD[1][c]  = fmaf(wv, lD[c],  accD[1][c]);
                accS2[1][c] = fmaf(wv, lS2[c], accS2[1][c]);
                accD2[1][c] = fmaf(wv, lD2[c], accD2[1][c]);
            }
        }
    }

    const float C1 = 6.5025f;
    const float C2 = 58.5225f;
    const int Hv = min(TH, W - y0);
    const int Wv = min(TW, W - x0);
    float sacc = 0.f, macc = 0.f;
#pragma unroll
    for (int rr = 0; rr < 2; ++rr) {
        int row = 2 * g + rr;
#pragma unroll
        for (int c = 0; c < 4; ++c) {
            float ms = accS[rr][c], md = accD[rr][c];
            float es = accS2[rr][c], ed = accD2[rr][c];
            float ms2 = ms * ms, md2 = md * md;
            float a  = 0.5f * (ms2 - md2);   // 2*mu1*mu2
            float bb = 0.5f * (ms2 + md2);   // mu1^2 + mu2^2
            float pq = 0.5f * (es - ed);     // 2*E[xy]
            float qq = 0.5f * (es + ed);     // E[x^2]+E[y^2]
            float V1 = (pq - a) + C2;
            float V2 = (qq - bb) + C2;
            float num = a + C1;
            float den = bb + C1;
            float inv = 1.0f / (den * V2);
            float sv = num * V1 * inv;
            float mv = V1 * den * inv;
            if (row < Hv && (4 * x + c) < Wv) { sacc += sv; macc += mv; }
        }
    }

#pragma unroll
    for (int o = 32; o > 0; o >>= 1) {
        sacc += __shfl_down(sacc, o);
        macc += __shfl_down(macc, o);
    }
    int wave = tid >> 6, lane = tid & 63;
    if (lane == 0) { red[0][wave] = sacc; red[1][wave] = macc; }
    __syncthreads();
    if (tid == 0) {
        float s = red[0][0] + red[0][1] + red[0][2] + red[0][3];
        float m = red[1][0] + red[1][1] + red[1][2] + red[1][3];
        partials[2 * part_idx] = s;
        partials[2 * part_idx + 1] = m;
    }
}

// ---------------------------------------------------------------------------
// Kernel A: L0 SSIM + full pool pyramid. Grid (8,16,16), 256 threads.
__global__ __launch_bounds__(256, 4) void ssim_l0_pool_kernel(
    const float* __restrict__ img1, const float* __restrict__ img2,
    float* __restrict__ l1a, float* __restrict__ l1b,
    float* __restrict__ l2a, float* __restrict__ l2b,
    float* __restrict__ l3a, float* __restrict__ l3b,
    float* __restrict__ l4a, float* __restrict__ l4b,
    float* __restrict__ partials)
{
    __shared__ __half2 hSD[SROWS * HSTRIDE];
    __shared__ __half2 hQ[SROWS * HSTRIDE];
    __shared__ float pl1a[16 * 36];
    __shared__ float pl1b[16 * 36];
    __shared__ float red[2][4];

    const int tid = threadIdx.x;
    const int tx = blockIdx.x, ty = blockIdx.y, b = blockIdx.z;
    const int x0 = tx * TW, y0 = ty * TH;
    const float* p1 = img1 + (size_t)b * 512 * 512;
    const float* p2 = img2 + (size_t)b * 512 * 512;

    float w[WS];
    gauss_weights(w);

    const bool interior = (x0 >= 8) && (x0 <= 512 - 72) && (y0 >= 5) && (y0 <= 512 - 37);

    // ---- Phase H: 672 tasks, 3 pipelined calls per thread.
    h_task(tid,       p1, p2, 512, x0, y0, interior, w, hSD, hQ);
    h_task(tid + 256, p1, p2, 512, x0, y0, interior, w, hSD, hQ);
    if (tid < 160)
        h_task(tid + 512, p1, p2, 512, x0, y0, interior, w, hSD, hQ);

    // ---- Pool L1 for this tile (all threads; exact fp32; source L1/L2-hot).
#pragma unroll
    for (int q = 0; q < 2; ++q) {
        int t = tid + q * 256;
        int r = t >> 5, c = t & 31;
        int gy = y0 + 2 * r, gx = x0 + 2 * c;
        const float* a0 = p1 + (size_t)gy * 512 + gx;
        const float* c0 = p2 + (size_t)gy * 512 + gx;
        float2 u0 = *(const float2*)a0;
        float2 u1 = *(const float2*)(a0 + 512);
        float2 t0 = *(const float2*)c0;
        float2 t1 = *(const float2*)(c0 + 512);
        float v1 = 0.25f * ((u0.x + u0.y) + (u1.x + u1.y));
        float v2 = 0.25f * ((t0.x + t0.y) + (t1.x + t1.y));
        size_t o1 = (size_t)b * 256 * 256 + (size_t)(y0 / 2 + r) * 256 + (x0 / 2 + c);
        l1a[o1] = v1;
        l1b[o1] = v2;
        pl1a[r * 36 + c] = v1;
        pl1b[r * 36 + c] = v2;
    }
    __syncthreads();   // h-planes AND pl1 complete

    // ---- Wave 0: deeper pools, register-hierarchical from pl1 (race-free).
    if (tid < 64) {
        int lane = tid;
        // L2: 8 rows x 16 cols
#pragma unroll
        for (int t = lane; t < 128; t += 64) {
            int r = t >> 4, c = t & 15;
            int R = 2 * r, C = 2 * c;
            float v1 = 0.25f * ((pl1a[R * 36 + C] + pl1a[R * 36 + C + 1]) +
                                (pl1a[(R + 1) * 36 + C] + pl1a[(R + 1) * 36 + C + 1]));
            float v2 = 0.25f * ((pl1b[R * 36 + C] + pl1b[R * 36 + C + 1]) +
                                (pl1b[(R + 1) * 36 + C] + pl1b[(R + 1) * 36 + C + 1]));
            size_t o = (size_t)b * 128 * 128 + (size_t)(y0 / 4 + r) * 128 + (x0 / 4 + c);
            l2a[o] = v1;
            l2b[o] = v2;
        }
        // L3: 4 rows x 8 cols (lanes 0..31)
        if (lane < 32) {
            int r = lane >> 3, c = lane & 7;
            float q1[2][2], q2[2][2];
#pragma unroll
            for (int i = 0; i < 2; ++i)
#pragma unroll
                for (int j = 0; j < 2; ++j) {
                    int R = 4 * r + 2 * i, C = 4 * c + 2 * j;
                    q1[i][j] = 0.25f * ((pl1a[R * 36 + C] + pl1a[R * 36 + C + 1]) +
                                        (pl1a[(R + 1) * 36 + C] + pl1a[(R + 1) * 36 + C + 1]));
                    q2[i][j] = 0.25f * ((pl1b[R * 36 + C] + pl1b[R * 36 + C + 1]) +
                                        (pl1b[(R + 1) * 36 + C] + pl1b[(R + 1) * 36 + C + 1]));
                }
            float v1 = 0.25f * ((q1[0][0] + q1[0][1]) + (q1[1][0] + q1[1][1]));
            float v2 = 0.25f * ((q2[0][0] + q2[0][1]) + (q2[1][0] + q2[1][1]));
            size_t o = (size_t)b * 64 * 64 + (size_t)(y0 / 8 + r) * 64 + (x0 / 8 + c);
            l3a[o] = v1;
            l3b[o] = v2;
        }
        // L4: 2 rows x 4 cols (lanes 0..7)
        if (lane < 8) {
            int r = lane >> 2, c = lane & 3;
            float p3a[2][2], p3b[2][2];
#pragma unroll
            for (int i3 = 0; i3 < 2; ++i3)
#pragma unroll
                for (int j3 = 0; j3 < 2; ++j3) {
                    float p2a[2][2], p2b[2][2];
#pragma unroll
                    for (int i2 = 0; i2 < 2; ++i2)
#pragma unroll
                        for (int j2 = 0; j2 < 2; ++j2) {
                            int R = 8 * r + 4 * i3 + 2 * i2;
                            int C = 8 * c + 4 * j3 + 2 * j2;
                            p2a[i2][j2] = 0.25f * ((pl1a[R * 36 + C] + pl1a[R * 36 + C + 1]) +
                                                   (pl1a[(R + 1) * 36 + C] + pl1a[(R + 1) * 36 + C + 1]));
                            p2b[i2][j2] = 0.25f * ((pl1b[R * 36 + C] + pl1b[R * 36 + C + 1]) +
                                                   (pl1b[(R + 1) * 36 + C] + pl1b[(R + 1) * 36 + C + 1]));
                        }
                    p3a[i3][j3] = 0.25f * ((p2a[0][0] + p2a[0][1]) + (p2a[1][0] + p2a[1][1]));
                    p3b[i3][j3] = 0.25f * ((p2b[0][0] + p2b[0][1]) + (p2b[1][0] + p2b[1][1]));
                }
            float v1 = 0.25f * ((p3a[0][0] + p3a[0][1]) + (p3a[1][0] + p3a[1][1]));
            float v2 = 0.25f * ((p3b[0][0] + p3b[0][1]) + (p3b[1][0] + p3b[1][1]));
            size_t o = (size_t)b * 32 * 32 + (size_t)(y0 / 16 + r) * 32 + (x0 / 16 + c);
            l4a[o] = v1;
            l4b[o] = v2;
        }
    }

    // ---- Phase V + reduction.
    int part_idx = ((b * 16 + ty) * 8) + tx;
    v_phase(512, x0, y0, w, hSD, hQ, red, partials, part_idx);
}

// ---------------------------------------------------------------------------
// Kernel B: SSIM levels 1..4. 688 blocks.
// Ranges: L1 [0,512)  L2 [512,640)  L3 [640,672)  L4 [672,688)
__global__ __launch_bounds__(256, 4) void ssim_rest_kernel(
    const float* __restrict__ l1a, const float* __restrict__ l1b,
    const float* __restrict__ l2a, const float* __restrict__ l2b,
    const float* __restrict__ l3a, const float* __restrict__ l3b,
    const float* __restrict__ l4a, const float* __restrict__ l4b,
    float* __restrict__ partials)   // already offset to L1 base
{
    __shared__ __half2 hSD[SROWS * HSTRIDE];
    __shared__ __half2 hQ[SROWS * HSTRIDE];
    __shared__ float red[2][4];

    const int tid = threadIdx.x;
    const int lin = blockIdx.x;
    int level, base;
    if (lin < 512)      { level = 1; base = 0; }
    else if (lin < 640) { level = 2; base = 512; }
    else if (lin < 672) { level = 3; base = 640; }
    else                { level = 4; base = 672; }
    const int Wt[4]   = {256, 128, 64, 32};
    const int ntxl[4] = {2, 1, 0, 0};
    const int ntyl[4] = {3, 2, 1, 0};
    const int idx = level - 1;
    const int W = Wt[idx];
    const int li = lin - base;
    const int tx = li & ((1 << ntxl[idx]) - 1);
    const int rem = li >> ntxl[idx];
    const int ty = rem & ((1 << ntyl[idx]) - 1);
    const int b = rem >> ntyl[idx];

    const float* ip1; const float* ip2;
    if (level == 1)      { ip1 = l1a; ip2 = l1b; }
    else if (level == 2) { ip1 = l2a; ip2 = l2b; }
    else if (level == 3) { ip1 = l3a; ip2 = l3b; }
    else                 { ip1 = l4a; ip2 = l4b; }
    const float* p1 = ip1 + (size_t)b * W * W;
    const float* p2 = ip2 + (size_t)b * W * W;

    const int x0 = tx * TW, y0 = ty * TH;

    float w[WS];
    gauss_weights(w);

    const bool interior = (x0 >= 8) && (x0 <= W - 72) && (y0 >= 5) && (y0 <= W - 37);

    h_task(tid,       p1, p2, W, x0, y0, interior, w, hSD, hQ);
    h_task(tid + 256, p1, p2, W, x0, y0, interior, w, hSD, hQ);
    if (tid < 160)
        h_task(tid + 512, p1, p2, W, x0, y0, interior, w, hSD, hQ);
    __syncthreads();

    v_phase(W, x0, y0, w, hSD, hQ, red, partials, lin);
}

// ---------------------------------------------------------------------------
__global__ __launch_bounds__(256) void finalize_kernel(
    const float* __restrict__ partials, float* __restrict__ out)
{
    __shared__ float lvl_s[5], lvl_m[5];
    __shared__ float red[2][4];
    const int nb[5] = {2048, 512, 128, 32, 16};
    const int off[5] = {0, 2048, 2560, 2688, 2720};
    const float npix[5] = {16.f * 512 * 512, 16.f * 256 * 256, 16.f * 128 * 128,
                           16.f * 64 * 64, 16.f * 32 * 32};
    const int tid = threadIdx.x;

    for (int l = 0; l < 5; ++l) {
        float s = 0.f, m = 0.f;
        for (int i = tid; i < nb[l]; i += 256) {
            s += partials[2 * (off[l] + i)];
            m += partials[2 * (off[l] + i) + 1];
        }
#pragma unroll
        for (int o = 32; o > 0; o >>= 1) {
            s += __shfl_down(s, o);
            m += __shfl_down(m, o);
        }
        int wave = tid >> 6, lane = tid & 63;
        if (lane == 0) { red[0][wave] = s; red[1][wave] = m; }
        __syncthreads();
        if (tid == 0) {
            lvl_s[l] = (red[0][0] + red[0][1] + red[0][2] + red[0][3]) / npix[l];
            lvl_m[l] = (red[1][0] + red[1][1] + red[1][2] + red[1][3]) / npix[l];
        }
        __syncthreads();
    }

    if (tid == 0) {
        const float w[5] = {0.0448f, 0.2856f, 0.3001f, 0.2363f, 0.1333f};
        float v = powf(lvl_m[0], w[0]) * powf(lvl_m[1], w[1]) * powf(lvl_m[2], w[2]) *
                  powf(lvl_m[3], w[3]) * powf(lvl_s[4], w[4]);
        v *= 0.5f;
        v = fminf(fmaxf(v, 0.f), 1.f);
        out[0] = v;
    }
}

extern "C" void kernel_launch(void* const* d_in, const int* in_sizes, int n_in,
                              void* d_out, int out_size, void* d_ws, size_t ws_size,
                              hipStream_t stream) {
    const float* img1 = (const float*)d_in[0];
    const float* img2 = (const float*)d_in[1];
    float* out = (float*)d_out;

    const int B = 16;

    float* wsf = (float*)d_ws;
    float* partials = wsf;
    float* p = wsf + 5472;
    float* l1a = p; p += (size_t)B * 256 * 256;
    float* l1b = p; p += (size_t)B * 256 * 256;
    float* l2a = p; p += (size_t)B * 128 * 128;
    float* l2b = p; p += (size_t)B * 128 * 128;
    float* l3a = p; p += (size_t)B * 64 * 64;
    float* l3b = p; p += (size_t)B * 64 * 64;
    float* l4a = p; p += (size_t)B * 32 * 32;
    float* l4b = p; p += (size_t)B * 32 * 32;

    dim3 block(256);

    ssim_l0_pool_kernel<<<dim3(8, 16, B), block, 0, stream>>>(
        img1, img2, l1a, l1b, l2a, l2b, l3a, l3b, l4a, l4b, partials);

    ssim_rest_kernel<<<dim3(688), block, 0, stream>>>(
        l1a, l1b, l2a, l2b, l3a, l3b, l4a, l4b, partials + 2 * 2048);

    finalize_kernel<<<1, block, 0, stream>>>(partials, out);
}

// Round 9
// 130.456 us; speedup vs baseline: 2.0202x; 1.9523x over previous
//
#include <hip/hip_runtime.h>
#include <hip/hip_fp16.h>
#include <math.h>

// MS-SSIM on (16,1,512,512) fp32, 5 levels, 11x11 gaussian (sigma=1.5), 2x2 avg-pool.
// Round-9 structure (3 dispatches) = R4 proven skeleton + fp16 LDS h-planes.
//   A) ssim_l0_pool_kernel (2048 blocks): L0 SSIM 64x32 tile + exact-fp32 pool
//      pyramid emission (L1 all-threads via LDS pl1; L2..L4 wave0 from pl1).
//   B) ssim_rest_kernel (688 blocks): SSIM levels 1..4 from pooled arrays.
//   C) finalize_kernel.
// Lessons applied:
//   - fp16 __half2 h-planes: LDS 50.7->27.6 KB, V-phase LDS reads halved
//     (validated R8: absmax 0.0).
//   - NO __launch_bounds__ min-waves clause (R8: it forced VGPR=64 -> 211 MB
//     scratch spill). Plain (256); compiler picks ~70-110 VGPR.
//   - Phase H as `#pragma unroll 1` grid-stride loop (R4 proven register shape;
//     R8's 3 inlined calls tripled live state).

#define WS 11
#define TW 64
#define TH 32
#define SROWS 42      // TH + 10 h-rows per tile
#define HSTRIDE 68    // h-plane row stride in __half2 entries (4B each)

__device__ __forceinline__ void gauss_weights(float* w) {
    float s = 0.f;
#pragma unroll
    for (int j = 0; j < WS; ++j) {
        float d = (float)(j - 5);
        float e = expf(-d * d / 4.5f);   // 2*sigma^2 = 4.5
        w[j] = e;
        s += e;
    }
    float inv = 1.f / s;
#pragma unroll
    for (int j = 0; j < WS; ++j) w[j] *= inv;
}

// One horizontal-conv task: h-row r, 4-col group xg (t = r*16+xg).
__device__ __forceinline__ void h_task(
    int t, const float* __restrict__ p1, const float* __restrict__ p2,
    int W, int x0, int y0, bool interior, const float* w,
    __half2* __restrict__ hSD, __half2* __restrict__ hQ)
{
    int r = t >> 4, xg = t & 15;
    int gy = y0 - 5 + r;
    int gxb = x0 - 8 + 4 * xg;
    float fs[20], fd[20];
    if (interior) {
        const float* r1p = p1 + (size_t)gy * W + gxb;
        const float* r2p = p2 + (size_t)gy * W + gxb;
#pragma unroll
        for (int k = 0; k < 5; ++k) {
            float4 a = *(const float4*)(r1p + 4 * k);
            float4 c = *(const float4*)(r2p + 4 * k);
            fs[4 * k]     = a.x + c.x;  fd[4 * k]     = a.x - c.x;
            fs[4 * k + 1] = a.y + c.y;  fd[4 * k + 1] = a.y - c.y;
            fs[4 * k + 2] = a.z + c.z;  fd[4 * k + 2] = a.z - c.z;
            fs[4 * k + 3] = a.w + c.w;  fd[4 * k + 3] = a.w - c.w;
        }
    } else if (gy >= 0 && gy < W) {
        const float* r1p = p1 + (size_t)gy * W;
        const float* r2p = p2 + (size_t)gy * W;
#pragma unroll
        for (int k = 0; k < 5; ++k) {
            int gx = gxb + 4 * k;
            float4 a = make_float4(0.f, 0.f, 0.f, 0.f);
            float4 c = make_float4(0.f, 0.f, 0.f, 0.f);
            if (gx >= 0 && gx + 3 < W) {
                a = *(const float4*)(r1p + gx);
                c = *(const float4*)(r2p + gx);
            } else if (gx + 3 >= 0 && gx < W) {
                float t1[4] = {0.f, 0.f, 0.f, 0.f};
                float t2[4] = {0.f, 0.f, 0.f, 0.f};
#pragma unroll
                for (int u = 0; u < 4; ++u) {
                    int gxx = gx + u;
                    if (gxx >= 0 && gxx < W) { t1[u] = r1p[gxx]; t2[u] = r2p[gxx]; }
                }
                a = make_float4(t1[0], t1[1], t1[2], t1[3]);
                c = make_float4(t2[0], t2[1], t2[2], t2[3]);
            }
            fs[4 * k]     = a.x + c.x;  fd[4 * k]     = a.x - c.x;
            fs[4 * k + 1] = a.y + c.y;  fd[4 * k + 1] = a.y - c.y;
            fs[4 * k + 2] = a.z + c.z;  fd[4 * k + 2] = a.z - c.z;
            fs[4 * k + 3] = a.w + c.w;  fd[4 * k + 3] = a.w - c.w;
        }
    } else {
#pragma unroll
        for (int k = 0; k < 20; ++k) { fs[k] = 0.f; fd[k] = 0.f; }
    }
    float qs[14], qd[14];
#pragma unroll
    for (int k = 0; k < 14; ++k) {
        qs[k] = fs[k + 3] * fs[k + 3];
        qd[k] = fd[k + 3] * fd[k + 3];
    }
    __half2 outSD[4], outQ[4];
#pragma unroll
    for (int c = 0; c < 4; ++c) {
        float aS = 0.f, aD = 0.f, aS2 = 0.f, aD2 = 0.f;
#pragma unroll
        for (int j = 0; j < WS; ++j) {
            float wj = w[j];
            aS  = fmaf(wj, fs[3 + c + j], aS);
            aD  = fmaf(wj, fd[3 + c + j], aD);
            aS2 = fmaf(wj, qs[c + j], aS2);
            aD2 = fmaf(wj, qd[c + j], aD2);
        }
        outSD[c] = __float22half2_rn(make_float2(aS, aD));
        outQ[c]  = __float22half2_rn(make_float2(aS2, aD2));
    }
    int ho = r * HSTRIDE + 4 * xg;
    *(float4*)&hSD[ho] = *(const float4*)outSD;
    *(float4*)&hQ[ho]  = *(const float4*)outQ;
}

// Phase V + SSIM + block reduction; writes partials[part_idx].
__device__ __forceinline__ void v_phase(
    int W, int x0, int y0, const float* w,
    const __half2* __restrict__ hSD, const __half2* __restrict__ hQ,
    float red[2][4], float* __restrict__ partials, int part_idx)
{
    const int tid = threadIdx.x;
    const int x = tid & 15;
    const int g = tid >> 4;
    float accS[2][4], accD[2][4], accS2[2][4], accD2[2][4];
#pragma unroll
    for (int rr = 0; rr < 2; ++rr)
#pragma unroll
        for (int c = 0; c < 4; ++c) {
            accS[rr][c] = 0.f; accD[rr][c] = 0.f;
            accS2[rr][c] = 0.f; accD2[rr][c] = 0.f;
        }

#pragma unroll
    for (int r = 0; r < 12; ++r) {
        int ho = (2 * g + r) * HSTRIDE + 4 * x;
        float4 rawSD = *(const float4*)&hSD[ho];
        float4 rawQ  = *(const float4*)&hQ[ho];
        const __half2* hpSD = (const __half2*)&rawSD;
        const __half2* hpQ  = (const __half2*)&rawQ;
        float lS[4], lD[4], lS2[4], lD2[4];
#pragma unroll
        for (int c = 0; c < 4; ++c) {
            float2 sd = __half22float2(hpSD[c]);
            float2 q  = __half22float2(hpQ[c]);
            lS[c] = sd.x; lD[c] = sd.y; lS2[c] = q.x; lD2[c] = q.y;
        }
        if (r < 11) {
            float wv = w[r];
#pragma unroll
            for (int c = 0; c < 4; ++c) {
                accS[0][c]  = fmaf(wv, lS[c],  accS[0][c]);
                accD[0][c]  = fmaf(wv, lD[c],  accD[0][c]);
                accS2[0][c] = fmaf(wv, lS2[c], accS2[0][c]);
                accD2[0][c] = fmaf(wv, lD2[c], accD2[0][c]);
            }
        }
        if (r >= 1) {
            float wv = w[r - 1];
#pragma unroll
            for (int c = 0; c < 4; ++c) {
                accS[1][c]  = fmaf(wv, lS[c],  accS[1][c]);
                accD[1][c]  = fmaf(wv, lD[c],  accD[1][c]);
                accS2[1][c] = fmaf(wv, lS2[c], accS2[1][c]);
                accD2[1][c] = fmaf(wv, lD2[c], accD2[1][c]);
            }
        }
    }

    const float C1 = 6.5025f;
    const float C2 = 58.5225f;
    const int Hv = min(TH, W - y0);
    const int Wv = min(TW, W - x0);
    float sacc = 0.f, macc = 0.f;
#pragma unroll
    for (int rr = 0; rr < 2; ++rr) {
        int row = 2 * g + rr;
#pragma unroll
        for (int c = 0; c < 4; ++c) {
            float ms = accS[rr][c], md = accD[rr][c];
            float es = accS2[rr][c], ed = accD2[rr][c];
            float ms2 = ms * ms, md2 = md * md;
            float a  = 0.5f * (ms2 - md2);   // 2*mu1*mu2
            float bb = 0.5f * (ms2 + md2);   // mu1^2 + mu2^2
            float pq = 0.5f * (es - ed);     // 2*E[xy]
            float qq = 0.5f * (es + ed);     // E[x^2]+E[y^2]
            float V1 = (pq - a) + C2;
            float V2 = (qq - bb) + C2;
            float num = a + C1;
            float den = bb + C1;
            float inv = 1.0f / (den * V2);
            float sv = num * V1 * inv;
            float mv = V1 * den * inv;
            if (row < Hv && (4 * x + c) < Wv) { sacc += sv; macc += mv; }
        }
    }

#pragma unroll
    for (int o = 32; o > 0; o >>= 1) {
        sacc += __shfl_down(sacc, o);
        macc += __shfl_down(macc, o);
    }
    int wave = tid >> 6, lane = tid & 63;
    if (lane == 0) { red[0][wave] = sacc; red[1][wave] = macc; }
    __syncthreads();
    if (tid == 0) {
        float s = red[0][0] + red[0][1] + red[0][2] + red[0][3];
        float m = red[1][0] + red[1][1] + red[1][2] + red[1][3];
        partials[2 * part_idx] = s;
        partials[2 * part_idx + 1] = m;
    }
}

// ---------------------------------------------------------------------------
// Kernel A: L0 SSIM + full pool pyramid. Grid (8,16,16), 256 threads.
__global__ __launch_bounds__(256) void ssim_l0_pool_kernel(
    const float* __restrict__ img1, const float* __restrict__ img2,
    float* __restrict__ l1a, float* __restrict__ l1b,
    float* __restrict__ l2a, float* __restrict__ l2b,
    float* __restrict__ l3a, float* __restrict__ l3b,
    float* __restrict__ l4a, float* __restrict__ l4b,
    float* __restrict__ partials)
{
    __shared__ __half2 hSD[SROWS * HSTRIDE];
    __shared__ __half2 hQ[SROWS * HSTRIDE];
    __shared__ float pl1a[16 * 36];
    __shared__ float pl1b[16 * 36];
    __shared__ float red[2][4];

    const int tid = threadIdx.x;
    const int tx = blockIdx.x, ty = blockIdx.y, b = blockIdx.z;
    const int x0 = tx * TW, y0 = ty * TH;
    const float* p1 = img1 + (size_t)b * 512 * 512;
    const float* p2 = img2 + (size_t)b * 512 * 512;

    float w[WS];
    gauss_weights(w);

    const bool interior = (x0 >= 8) && (x0 <= 512 - 72) && (y0 >= 5) && (y0 <= 512 - 37);

    // ---- Phase H: grid-stride loop (one task's registers live at a time).
#pragma unroll 1
    for (int t = tid; t < SROWS * 16; t += 256)
        h_task(t, p1, p2, 512, x0, y0, interior, w, hSD, hQ);

    // ---- Pool L1 for this tile (all threads; exact fp32; source L1/L2-hot).
#pragma unroll 1
    for (int q = 0; q < 2; ++q) {
        int t = tid + q * 256;
        int r = t >> 5, c = t & 31;
        int gy = y0 + 2 * r, gx = x0 + 2 * c;
        const float* a0 = p1 + (size_t)gy * 512 + gx;
        const float* c0 = p2 + (size_t)gy * 512 + gx;
        float2 u0 = *(const float2*)a0;
        float2 u1 = *(const float2*)(a0 + 512);
        float2 t0 = *(const float2*)c0;
        float2 t1 = *(const float2*)(c0 + 512);
        float v1 = 0.25f * ((u0.x + u0.y) + (u1.x + u1.y));
        float v2 = 0.25f * ((t0.x + t0.y) + (t1.x + t1.y));
        size_t o1 = (size_t)b * 256 * 256 + (size_t)(y0 / 2 + r) * 256 + (x0 / 2 + c);
        l1a[o1] = v1;
        l1b[o1] = v2;
        pl1a[r * 36 + c] = v1;
        pl1b[r * 36 + c] = v2;
    }
    __syncthreads();   // h-planes AND pl1 complete

    // ---- Wave 0: deeper pools, register-hierarchical from pl1 (race-free).
    if (tid < 64) {
        int lane = tid;
        // L2: 8 rows x 16 cols
#pragma unroll
        for (int t = lane; t < 128; t += 64) {
            int r = t >> 4, c = t & 15;
            int R = 2 * r, C = 2 * c;
            float v1 = 0.25f * ((pl1a[R * 36 + C] + pl1a[R * 36 + C + 1]) +
                                (pl1a[(R + 1) * 36 + C] + pl1a[(R + 1) * 36 + C + 1]));
            float v2 = 0.25f * ((pl1b[R * 36 + C] + pl1b[R * 36 + C + 1]) +
                                (pl1b[(R + 1) * 36 + C] + pl1b[(R + 1) * 36 + C + 1]));
            size_t o = (size_t)b * 128 * 128 + (size_t)(y0 / 4 + r) * 128 + (x0 / 4 + c);
            l2a[o] = v1;
            l2b[o] = v2;
        }
        // L3: 4 rows x 8 cols (lanes 0..31)
        if (lane < 32) {
            int r = lane >> 3, c = lane & 7;
            float q1[2][2], q2[2][2];
#pragma unroll
            for (int i = 0; i < 2; ++i)
#pragma unroll
                for (int j = 0; j < 2; ++j) {
                    int R = 4 * r + 2 * i, C = 4 * c + 2 * j;
                    q1[i][j] = 0.25f * ((pl1a[R * 36 + C] + pl1a[R * 36 + C + 1]) +
                                        (pl1a[(R + 1) * 36 + C] + pl1a[(R + 1) * 36 + C + 1]));
                    q2[i][j] = 0.25f * ((pl1b[R * 36 + C] + pl1b[R * 36 + C + 1]) +
                                        (pl1b[(R + 1) * 36 + C] + pl1b[(R + 1) * 36 + C + 1]));
                }
            float v1 = 0.25f * ((q1[0][0] + q1[0][1]) + (q1[1][0] + q1[1][1]));
            float v2 = 0.25f * ((q2[0][0] + q2[0][1]) + (q2[1][0] + q2[1][1]));
            size_t o = (size_t)b * 64 * 64 + (size_t)(y0 / 8 + r) * 64 + (x0 / 8 + c);
            l3a[o] = v1;
            l3b[o] = v2;
        }
        // L4: 2 rows x 4 cols (lanes 0..7)
        if (lane < 8) {
            int r = lane >> 2, c = lane & 3;
            float p3a[2][2], p3b[2][2];
#pragma unroll
            for (int i3 = 0; i3 < 2; ++i3)
#pragma unroll
                for (int j3 = 0; j3 < 2; ++j3) {
                    float p2a[2][2], p2b[2][2];
#pragma unroll
                    for (int i2 = 0; i2 < 2; ++i2)
#pragma unroll
                        for (int j2 = 0; j2 < 2; ++j2) {
                            int R = 8 * r + 4 * i3 + 2 * i2;
                            int C = 8 * c + 4 * j3 + 2 * j2;
                            p2a[i2][j2] = 0.25f * ((pl1a[R * 36 + C] + pl1a[R * 36 + C + 1]) +
                                                   (pl1a[(R + 1) * 36 + C] + pl1a[(R + 1) * 36 + C + 1]));
                            p2b[i2][j2] = 0.25f * ((pl1b[R * 36 + C] + pl1b[R * 36 + C + 1]) +
                                                   (pl1b[(R + 1) * 36 + C] + pl1b[(R + 1) * 36 + C + 1]));
                        }
                    p3a[i3][j3] = 0.25f * ((p2a[0][0] + p2a[0][1]) + (p2a[1][0] + p2a[1][1]));
                    p3b[i3][j3] = 0.25f * ((p2b[0][0] + p2b[0][1]) + (p2b[1][0] + p2b[1][1]));
                }
            float v1 = 0.25f * ((p3a[0][0] + p3a[0][1]) + (p3a[1][0] + p3a[1][1]));
            float v2 = 0.25f * ((p3b[0][0] + p3b[0][1]) + (p3b[1][0] + p3b[1][1]));
            size_t o = (size_t)b * 32 * 32 + (size_t)(y0 / 16 + r) * 32 + (x0 / 16 + c);
            l4a[o] = v1;
            l4b[o] = v2;
        }
    }

    // ---- Phase V + reduction.
    int part_idx = ((b * 16 + ty) * 8) + tx;
    v_phase(512, x0, y0, w, hSD, hQ, red, partials, part_idx);
}

// ---------------------------------------------------------------------------
// Kernel B: SSIM levels 1..4. 688 blocks.
// Ranges: L1 [0,512)  L2 [512,640)  L3 [640,672)  L4 [672,688)
__global__ __launch_bounds__(256) void ssim_rest_kernel(
    const float* __restrict__ l1a, const float* __restrict__ l1b,
    const float* __restrict__ l2a, const float* __restrict__ l2b,
    const float* __restrict__ l3a, const float* __restrict__ l3b,
    const float* __restrict__ l4a, const float* __restrict__ l4b,
    float* __restrict__ partials)   // already offset to L1 base
{
    __shared__ __half2 hSD[SROWS * HSTRIDE];
    __shared__ __half2 hQ[SROWS * HSTRIDE];
    __shared__ float red[2][4];

    const int tid = threadIdx.x;
    const int lin = blockIdx.x;
    int level, base;
    if (lin < 512)      { level = 1; base = 0; }
    else if (lin < 640) { level = 2; base = 512; }
    else if (lin < 672) { level = 3; base = 640; }
    else                { level = 4; base = 672; }
    const int Wt[4]   = {256, 128, 64, 32};
    const int ntxl[4] = {2, 1, 0, 0};
    const int ntyl[4] = {3, 2, 1, 0};
    const int idx = level - 1;
    const int W = Wt[idx];
    const int li = lin - base;
    const int tx = li & ((1 << ntxl[idx]) - 1);
    const int rem = li >> ntxl[idx];
    const int ty = rem & ((1 << ntyl[idx]) - 1);
    const int b = rem >> ntyl[idx];

    const float* ip1; const float* ip2;
    if (level == 1)      { ip1 = l1a; ip2 = l1b; }
    else if (level == 2) { ip1 = l2a; ip2 = l2b; }
    else if (level == 3) { ip1 = l3a; ip2 = l3b; }
    else                 { ip1 = l4a; ip2 = l4b; }
    const float* p1 = ip1 + (size_t)b * W * W;
    const float* p2 = ip2 + (size_t)b * W * W;

    const int x0 = tx * TW, y0 = ty * TH;

    float w[WS];
    gauss_weights(w);

    const bool interior = (x0 >= 8) && (x0 <= W - 72) && (y0 >= 5) && (y0 <= W - 37);

#pragma unroll 1
    for (int t = tid; t < SROWS * 16; t += 256)
        h_task(t, p1, p2, W, x0, y0, interior, w, hSD, hQ);
    __syncthreads();

    v_phase(W, x0, y0, w, hSD, hQ, red, partials, lin);
}

// ---------------------------------------------------------------------------
__global__ __launch_bounds__(256) void finalize_kernel(
    const float* __restrict__ partials, float* __restrict__ out)
{
    __shared__ float lvl_s[5], lvl_m[5];
    __shared__ float red[2][4];
    const int nb[5] = {2048, 512, 128, 32, 16};
    const int off[5] = {0, 2048, 2560, 2688, 2720};
    const float npix[5] = {16.f * 512 * 512, 16.f * 256 * 256, 16.f * 128 * 128,
                           16.f * 64 * 64, 16.f * 32 * 32};
    const int tid = threadIdx.x;

    for (int l = 0; l < 5; ++l) {
        float s = 0.f, m = 0.f;
        for (int i = tid; i < nb[l]; i += 256) {
            s += partials[2 * (off[l] + i)];
            m += partials[2 * (off[l] + i) + 1];
        }
#pragma unroll
        for (int o = 32; o > 0; o >>= 1) {
            s += __shfl_down(s, o);
            m += __shfl_down(m, o);
        }
        int wave = tid >> 6, lane = tid & 63;
        if (lane == 0) { red[0][wave] = s; red[1][wave] = m; }
        __syncthreads();
        if (tid == 0) {
            lvl_s[l] = (red[0][0] + red[0][1] + red[0][2] + red[0][3]) / npix[l];
            lvl_m[l] = (red[1][0] + red[1][1] + red[1][2] + red[1][3]) / npix[l];
        }
        __syncthreads();
    }

    if (tid == 0) {
        const float w[5] = {0.0448f, 0.2856f, 0.3001f, 0.2363f, 0.1333f};
        float v = powf(lvl_m[0], w[0]) * powf(lvl_m[1], w[1]) * powf(lvl_m[2], w[2]) *
                  powf(lvl_m[3], w[3]) * powf(lvl_s[4], w[4]);
        v *= 0.5f;
        v = fminf(fmaxf(v, 0.f), 1.f);
        out[0] = v;
    }
}

extern "C" void kernel_launch(void* const* d_in, const int* in_sizes, int n_in,
                              void* d_out, int out_size, void* d_ws, size_t ws_size,
                              hipStream_t stream) {
    const float* img1 = (const float*)d_in[0];
    const float* img2 = (const float*)d_in[1];
    float* out = (float*)d_out;

    const int B = 16;

    float* wsf = (float*)d_ws;
    float* partials = wsf;
    float* p = wsf + 5472;
    float* l1a = p; p += (size_t)B * 256 * 256;
    float* l1b = p; p += (size_t)B * 256 * 256;
    float* l2a = p; p += (size_t)B * 128 * 128;
    float* l2b = p; p += (size_t)B * 128 * 128;
    float* l3a = p; p += (size_t)B * 64 * 64;
    float* l3b = p; p += (size_t)B * 64 * 64;
    float* l4a = p; p += (size_t)B * 32 * 32;
    float* l4b = p; p += (size_t)B * 32 * 32;

    dim3 block(256);

    ssim_l0_pool_kernel<<<dim3(8, 16, B), block, 0, stream>>>(
        img1, img2, l1a, l1b, l2a, l2b, l3a, l3b, l4a, l4b, partials);

    ssim_rest_kernel<<<dim3(688), block, 0, stream>>>(
        l1a, l1b, l2a, l2b, l3a, l3b, l4a, l4b, partials + 2 * 2048);

    finalize_kernel<<<1, block, 0, stream>>>(partials, out);
}

// Round 10
// 130.349 us; speedup vs baseline: 2.0219x; 1.0008x over previous
//
#include <hip/hip_runtime.h>
#include <hip/hip_fp16.h>
#include <math.h>

// MS-SSIM on (16,1,512,512) fp32, 5 levels, 11x11 gaussian (sigma=1.5), 2x2 avg-pool.
// Round-10 structure (3 dispatches):
//   A) ssim_l0_pool_kernel (2048 blocks): async-stage 42x80 input tile (both
//      images) into LDS via global_load_lds (width=16), zero-fix OOB halo,
//      then L0 SSIM 64x32 tile (phase H from LDS -> fp16 h-planes, phase V in
//      registers) + exact-fp32 pool pyramid (L1 all-threads from staged LDS;
//      L2..L4 wave0 from pl1).
//   B) ssim_rest_kernel (688 blocks): same staged pipeline for levels 1..4.
//   C) finalize_kernel.
// Lessons applied:
//   - R9: phase H was global-latency-bound (VALUBusy 42%) -> async bulk
//     staging, one vmcnt drain per block (the __syncthreads does it).
//   - fp16 __half2 h-planes validated (R8/R9: absmax 0.0).
//   - No __launch_bounds__ min-waves clause (R8: forced VGPR=64 -> 211MB spill).
//   - Boundary handling via clamped staging addresses + post-stage zero-fix
//     (bit-exact with reference zero padding).

#define WS 11
#define TW 64
#define TH 32
#define SROWS 42      // TH + 10 h-rows per tile
#define SSTRIDE 80    // staged tile row stride (floats), contiguous for staging
#define SFLOATS (SROWS * SSTRIDE)   // 3360
#define SALLOC 3584   // 14 chunks * 256 floats (stage granularity), tail unused
#define HSTRIDE 64    // h-plane row stride in __half2 entries (4B each)
#define PL1S 34       // pl1 row stride (shaved to fit 3 blocks/CU)

typedef const __attribute__((address_space(1))) void gvoid_t;
typedef __attribute__((address_space(3))) void lvoid_t;

__device__ __forceinline__ void gauss_weights(float* w) {
    float s = 0.f;
#pragma unroll
    for (int j = 0; j < WS; ++j) {
        float d = (float)(j - 5);
        float e = expf(-d * d / 4.5f);   // 2*sigma^2 = 4.5
        w[j] = e;
        s += e;
    }
    float inv = 1.f / s;
#pragma unroll
    for (int j = 0; j < WS; ++j) w[j] *= inv;
}

// Async-stage the 42x80 halo tile of both images into LDS (clamped addresses;
// OOB cells fixed to zero afterwards by zero_fix). 14 chunks of 256 floats,
// round-robin across the block's 4 waves; LDS dest is contiguous per chunk
// (wave-uniform base + lane*16), global src per-lane.
__device__ __forceinline__ void stage_tile(
    const float* __restrict__ g1, const float* __restrict__ g2,
    int H, int W, int x0, int y0,
    float* __restrict__ s1, float* __restrict__ s2, int tid)
{
    const int lane = tid & 63;
    const int wave = tid >> 6;
    for (int c = wave; c < 14; c += 4) {
        int f = c * 256 + lane * 4;
        int row = f / 80;
        int col = f - row * 80;
        int gy = y0 - 5 + row;
        gy = max(0, min(H - 1, gy));
        int gx = x0 - 8 + col;
        gx = max(0, min(W - 4, gx));
        const float* p1 = g1 + (size_t)gy * W + gx;
        const float* p2 = g2 + (size_t)gy * W + gx;
        __builtin_amdgcn_global_load_lds((gvoid_t*)p1, (lvoid_t*)(s1 + f), 16, 0, 0);
        __builtin_amdgcn_global_load_lds((gvoid_t*)p2, (lvoid_t*)(s2 + f), 16, 0, 0);
    }
}

__device__ __forceinline__ void zero_fix(
    int H, int W, int x0, int y0,
    float* __restrict__ s1, float* __restrict__ s2, int tid)
{
    bool anyOOB = (y0 < 5) || (y0 + 37 > H) || (x0 < 8) || (x0 + 72 > W);
    if (anyOOB) {
        for (int t = tid; t < SFLOATS; t += 256) {
            int r = t / 80, c = t - (t / 80) * 80;
            int gy = y0 - 5 + r, gx = x0 - 8 + c;
            if (gy < 0 || gy >= H || gx < 0 || gx >= W) {
                s1[t] = 0.f;
                s2[t] = 0.f;
            }
        }
    }
}

// One horizontal-conv task from the staged LDS tile: h-row r, 4-col group xg.
__device__ __forceinline__ void h_task(
    int t, const float* __restrict__ s1, const float* __restrict__ s2,
    const float* w, __half2* __restrict__ hSD, __half2* __restrict__ hQ)
{
    int r = t >> 4, xg = t & 15;
    int sb = r * SSTRIDE + 4 * xg;
    float f1[20], f2[20];
#pragma unroll
    for (int k = 0; k < 5; ++k) {
        float4 a = *(const float4*)&s1[sb + 4 * k];
        float4 c = *(const float4*)&s2[sb + 4 * k];
        f1[4 * k] = a.x; f1[4 * k + 1] = a.y; f1[4 * k + 2] = a.z; f1[4 * k + 3] = a.w;
        f2[4 * k] = c.x; f2[4 * k + 1] = c.y; f2[4 * k + 2] = c.z; f2[4 * k + 3] = c.w;
    }
    float fs[20], fd[20];
#pragma unroll
    for (int k = 0; k < 20; ++k) {
        fs[k] = f1[k] + f2[k];
        fd[k] = f1[k] - f2[k];
    }
    float qs[14], qd[14];
#pragma unroll
    for (int k = 0; k < 14; ++k) {
        qs[k] = fs[k + 3] * fs[k + 3];
        qd[k] = fd[k + 3] * fd[k + 3];
    }
    __half2 outSD[4], outQ[4];
#pragma unroll
    for (int c = 0; c < 4; ++c) {
        float aS = 0.f, aD = 0.f, aS2 = 0.f, aD2 = 0.f;
#pragma unroll
        for (int j = 0; j < WS; ++j) {
            float wj = w[j];
            aS  = fmaf(wj, fs[3 + c + j], aS);
            aD  = fmaf(wj, fd[3 + c + j], aD);
            aS2 = fmaf(wj, qs[c + j], aS2);
            aD2 = fmaf(wj, qd[c + j], aD2);
        }
        outSD[c] = __float22half2_rn(make_float2(aS, aD));
        outQ[c]  = __float22half2_rn(make_float2(aS2, aD2));
    }
    int ho = r * HSTRIDE + 4 * xg;
    *(float4*)&hSD[ho] = *(const float4*)outSD;
    *(float4*)&hQ[ho]  = *(const float4*)outQ;
}

// Phase V + SSIM + block reduction; writes partials[part_idx].
__device__ __forceinline__ void v_phase(
    int W, int x0, int y0, const float* w,
    const __half2* __restrict__ hSD, const __half2* __restrict__ hQ,
    float red[2][4], float* __restrict__ partials, int part_idx)
{
    const int tid = threadIdx.x;
    const int x = tid & 15;
    const int g = tid >> 4;
    float accS[2][4], accD[2][4], accS2[2][4], accD2[2][4];
#pragma unroll
    for (int rr = 0; rr < 2; ++rr)
#pragma unroll
        for (int c = 0; c < 4; ++c) {
            accS[rr][c] = 0.f; accD[rr][c] = 0.f;
            accS2[rr][c] = 0.f; accD2[rr][c] = 0.f;
        }

#pragma unroll
    for (int r = 0; r < 12; ++r) {
        int ho = (2 * g + r) * HSTRIDE + 4 * x;
        float4 rawSD = *(const float4*)&hSD[ho];
        float4 rawQ  = *(const float4*)&hQ[ho];
        const __half2* hpSD = (const __half2*)&rawSD;
        const __half2* hpQ  = (const __half2*)&rawQ;
        float lS[4], lD[4], lS2[4], lD2[4];
#pragma unroll
        for (int c = 0; c < 4; ++c) {
            float2 sd = __half22float2(hpSD[c]);
            float2 q  = __half22float2(hpQ[c]);
            lS[c] = sd.x; lD[c] = sd.y; lS2[c] = q.x; lD2[c] = q.y;
        }
        if (r < 11) {
            float wv = w[r];
#pragma unroll
            for (int c = 0; c < 4; ++c) {
                accS[0][c]  = fmaf(wv, lS[c],  accS[0][c]);
                accD[0][c]  = fmaf(wv, lD[c],  accD[0][c]);
                accS2[0][c] = fmaf(wv, lS2[c], accS2[0][c]);
                accD2[0][c] = fmaf(wv, lD2[c], accD2[0][c]);
            }
        }
        if (r >= 1) {
            float wv = w[r - 1];
#pragma unroll
            for (int c = 0; c < 4; ++c) {
                accS[1][c]  = fmaf(wv, lS[c],  accS[1][c]);
                accD[1][c]  = fmaf(wv, lD[c],  accD[1][c]);
                accS2[1][c] = fmaf(wv, lS2[c], accS2[1][c]);
                accD2[1][c] = fmaf(wv, lD2[c], accD2[1][c]);
            }
        }
    }

    const float C1 = 6.5025f;
    const float C2 = 58.5225f;
    const int Hv = min(TH, W - y0);
    const int Wv = min(TW, W - x0);
    float sacc = 0.f, macc = 0.f;
#pragma unroll
    for (int rr = 0; rr < 2; ++rr) {
        int row = 2 * g + rr;
#pragma unroll
        for (int c = 0; c < 4; ++c) {
            float ms = accS[rr][c], md = accD[rr][c];
            float es = accS2[rr][c], ed = accD2[rr][c];
            float ms2 = ms * ms, md2 = md * md;
            float a  = 0.5f * (ms2 - md2);   // 2*mu1*mu2
            float bb = 0.5f * (ms2 + md2);   // mu1^2 + mu2^2
            float pq = 0.5f * (es - ed);     // 2*E[xy]
            float qq = 0.5f * (es + ed);     // E[x^2]+E[y^2]
            float V1 = (pq - a) + C2;
            float V2 = (qq - bb) + C2;
            float num = a + C1;
            float den = bb + C1;
            float inv = 1.0f / (den * V2);
            float sv = num * V1 * inv;
            float mv = V1 * den * inv;
            if (row < Hv && (4 * x + c) < Wv) { sacc += sv; macc += mv; }
        }
    }

#pragma unroll
    for (int o = 32; o > 0; o >>= 1) {
        sacc += __shfl_down(sacc, o);
        macc += __shfl_down(macc, o);
    }
    int wave = tid >> 6, lane = tid & 63;
    if (lane == 0) { red[0][wave] = sacc; red[1][wave] = macc; }
    __syncthreads();
    if (tid == 0) {
        float s = red[0][0] + red[0][1] + red[0][2] + red[0][3];
        float m = red[1][0] + red[1][1] + red[1][2] + red[1][3];
        partials[2 * part_idx] = s;
        partials[2 * part_idx + 1] = m;
    }
}

// ---------------------------------------------------------------------------
// Kernel A: L0 SSIM + full pool pyramid. Grid (8,16,16), 256 threads.
// LDS budget: 2*14336 + 2*10752 + 2*2176 + 32 = 54560 B -> 3 blocks/CU.
__global__ __launch_bounds__(256) void ssim_l0_pool_kernel(
    const float* __restrict__ img1, const float* __restrict__ img2,
    float* __restrict__ l1a, float* __restrict__ l1b,
    float* __restrict__ l2a, float* __restrict__ l2b,
    float* __restrict__ l3a, float* __restrict__ l3b,
    float* __restrict__ l4a, float* __restrict__ l4b,
    float* __restrict__ partials)
{
    __shared__ float s1[SALLOC];
    __shared__ float s2[SALLOC];
    __shared__ __half2 hSD[SROWS * HSTRIDE];
    __shared__ __half2 hQ[SROWS * HSTRIDE];
    __shared__ float pl1a[16 * PL1S];
    __shared__ float pl1b[16 * PL1S];
    __shared__ float red[2][4];

    const int tid = threadIdx.x;
    const int tx = blockIdx.x, ty = blockIdx.y, b = blockIdx.z;
    const int x0 = tx * TW, y0 = ty * TH;
    const float* p1 = img1 + (size_t)b * 512 * 512;
    const float* p2 = img2 + (size_t)b * 512 * 512;

    // ---- Async stage both image tiles into LDS.
    stage_tile(p1, p2, 512, 512, x0, y0, s1, s2, tid);

    float w[WS];
    gauss_weights(w);   // overlaps with staging latency

    __syncthreads();    // drains vmcnt (compiler emits full waitcnt) + barrier
    zero_fix(512, 512, x0, y0, s1, s2, tid);
    __syncthreads();

    // ---- Phase H from LDS (no boundary branches at all).
#pragma unroll 1
    for (int t = tid; t < SROWS * 16; t += 256)
        h_task(t, s1, s2, w, hSD, hQ);

    // ---- Pool L1 from staged LDS (exact fp32, reference grouping).
#pragma unroll 1
    for (int q = 0; q < 2; ++q) {
        int t = tid + q * 256;
        int r = t >> 5, c = t & 31;
        int si = (5 + 2 * r) * SSTRIDE + (8 + 2 * c);
        float2 u0 = *(const float2*)&s1[si];
        float2 u1 = *(const float2*)&s1[si + SSTRIDE];
        float2 t0 = *(const float2*)&s2[si];
        float2 t1 = *(const float2*)&s2[si + SSTRIDE];
        float v1 = 0.25f * ((u0.x + u0.y) + (u1.x + u1.y));
        float v2 = 0.25f * ((t0.x + t0.y) + (t1.x + t1.y));
        size_t o1 = (size_t)b * 256 * 256 + (size_t)(y0 / 2 + r) * 256 + (x0 / 2 + c);
        l1a[o1] = v1;
        l1b[o1] = v2;
        pl1a[r * PL1S + c] = v1;
        pl1b[r * PL1S + c] = v2;
    }
    __syncthreads();   // h-planes AND pl1 complete

    // ---- Wave 0: deeper pools, register-hierarchical from pl1 (race-free).
    if (tid < 64) {
        int lane = tid;
        // L2: 8 rows x 16 cols
#pragma unroll
        for (int t = lane; t < 128; t += 64) {
            int r = t >> 4, c = t & 15;
            int R = 2 * r, C = 2 * c;
            float v1 = 0.25f * ((pl1a[R * PL1S + C] + pl1a[R * PL1S + C + 1]) +
                                (pl1a[(R + 1) * PL1S + C] + pl1a[(R + 1) * PL1S + C + 1]));
            float v2 = 0.25f * ((pl1b[R * PL1S + C] + pl1b[R * PL1S + C + 1]) +
                                (pl1b[(R + 1) * PL1S + C] + pl1b[(R + 1) * PL1S + C + 1]));
            size_t o = (size_t)b * 128 * 128 + (size_t)(y0 / 4 + r) * 128 + (x0 / 4 + c);
            l2a[o] = v1;
            l2b[o] = v2;
        }
        // L3: 4 rows x 8 cols (lanes 0..31)
        if (lane < 32) {
            int r = lane >> 3, c = lane & 7;
            float q1[2][2], q2[2][2];
#pragma unroll
            for (int i = 0; i < 2; ++i)
#pragma unroll
                for (int j = 0; j < 2; ++j) {
                    int R = 4 * r + 2 * i, C = 4 * c + 2 * j;
                    q1[i][j] = 0.25f * ((pl1a[R * PL1S + C] + pl1a[R * PL1S + C + 1]) +
                                        (pl1a[(R + 1) * PL1S + C] + pl1a[(R + 1) * PL1S + C + 1]));
                    q2[i][j] = 0.25f * ((pl1b[R * PL1S + C] + pl1b[R * PL1S + C + 1]) +
                                        (pl1b[(R + 1) * PL1S + C] + pl1b[(R + 1) * PL1S + C + 1]));
                }
            float v1 = 0.25f * ((q1[0][0] + q1[0][1]) + (q1[1][0] + q1[1][1]));
            float v2 = 0.25f * ((q2[0][0] + q2[0][1]) + (q2[1][0] + q2[1][1]));
            size_t o = (size_t)b * 64 * 64 + (size_t)(y0 / 8 + r) * 64 + (x0 / 8 + c);
            l3a[o] = v1;
            l3b[o] = v2;
        }
        // L4: 2 rows x 4 cols (lanes 0..7)
        if (lane < 8) {
            int r = lane >> 2, c = lane & 3;
            float p3a[2][2], p3b[2][2];
#pragma unroll
            for (int i3 = 0; i3 < 2; ++i3)
#pragma unroll
                for (int j3 = 0; j3 < 2; ++j3) {
                    float p2a[2][2], p2b[2][2];
#pragma unroll
                    for (int i2 = 0; i2 < 2; ++i2)
#pragma unroll
                        for (int j2 = 0; j2 < 2; ++j2) {
                            int R = 8 * r + 4 * i3 + 2 * i2;
                            int C = 8 * c + 4 * j3 + 2 * j2;
                            p2a[i2][j2] = 0.25f * ((pl1a[R * PL1S + C] + pl1a[R * PL1S + C + 1]) +
                                                   (pl1a[(R + 1) * PL1S + C] + pl1a[(R + 1) * PL1S + C + 1]));
                            p2b[i2][j2] = 0.25f * ((pl1b[R * PL1S + C] + pl1b[R * PL1S + C + 1]) +
                                                   (pl1b[(R + 1) * PL1S + C] + pl1b[(R + 1) * PL1S + C + 1]));
                        }
                    p3a[i3][j3] = 0.25f * ((p2a[0][0] + p2a[0][1]) + (p2a[1][0] + p2a[1][1]));
                    p3b[i3][j3] = 0.25f * ((p2b[0][0] + p2b[0][1]) + (p2b[1][0] + p2b[1][1]));
                }
            float v1 = 0.25f * ((p3a[0][0] + p3a[0][1]) + (p3a[1][0] + p3a[1][1]));
            float v2 = 0.25f * ((p3b[0][0] + p3b[0][1]) + (p3b[1][0] + p3b[1][1]));
            size_t o = (size_t)b * 32 * 32 + (size_t)(y0 / 16 + r) * 32 + (x0 / 16 + c);
            l4a[o] = v1;
            l4b[o] = v2;
        }
    }

    // ---- Phase V + reduction.
    int part_idx = ((b * 16 + ty) * 8) + tx;
    v_phase(512, x0, y0, w, hSD, hQ, red, partials, part_idx);
}

// ---------------------------------------------------------------------------
// Kernel B: SSIM levels 1..4. 688 blocks.
// Ranges: L1 [0,512)  L2 [512,640)  L3 [640,672)  L4 [672,688)
__global__ __launch_bounds__(256) void ssim_rest_kernel(
    const float* __restrict__ l1a, const float* __restrict__ l1b,
    const float* __restrict__ l2a, const float* __restrict__ l2b,
    const float* __restrict__ l3a, const float* __restrict__ l3b,
    const float* __restrict__ l4a, const float* __restrict__ l4b,
    float* __restrict__ partials)   // already offset to L1 base
{
    __shared__ float s1[SALLOC];
    __shared__ float s2[SALLOC];
    __shared__ __half2 hSD[SROWS * HSTRIDE];
    __shared__ __half2 hQ[SROWS * HSTRIDE];
    __shared__ float red[2][4];

    const int tid = threadIdx.x;
    const int lin = blockIdx.x;
    int level, base;
    if (lin < 512)      { level = 1; base = 0; }
    else if (lin < 640) { level = 2; base = 512; }
    else if (lin < 672) { level = 3; base = 640; }
    else                { level = 4; base = 672; }
    const int Wt[4]   = {256, 128, 64, 32};
    const int ntxl[4] = {2, 1, 0, 0};
    const int ntyl[4] = {3, 2, 1, 0};
    const int idx = level - 1;
    const int W = Wt[idx];
    const int li = lin - base;
    const int tx = li & ((1 << ntxl[idx]) - 1);
    const int rem = li >> ntxl[idx];
    const int ty = rem & ((1 << ntyl[idx]) - 1);
    const int b = rem >> ntyl[idx];

    const float* ip1; const float* ip2;
    if (level == 1)      { ip1 = l1a; ip2 = l1b; }
    else if (level == 2) { ip1 = l2a; ip2 = l2b; }
    else if (level == 3) { ip1 = l3a; ip2 = l3b; }
    else                 { ip1 = l4a; ip2 = l4b; }
    const float* p1 = ip1 + (size_t)b * W * W;
    const float* p2 = ip2 + (size_t)b * W * W;

    const int x0 = tx * TW, y0 = ty * TH;

    stage_tile(p1, p2, W, W, x0, y0, s1, s2, tid);

    float w[WS];
    gauss_weights(w);

    __syncthreads();
    zero_fix(W, W, x0, y0, s1, s2, tid);
    __syncthreads();

#pragma unroll 1
    for (int t = tid; t < SROWS * 16; t += 256)
        h_task(t, s1, s2, w, hSD, hQ);
    __syncthreads();

    v_phase(W, x0, y0, w, hSD, hQ, red, partials, lin);
}

// ---------------------------------------------------------------------------
__global__ __launch_bounds__(256) void finalize_kernel(
    const float* __restrict__ partials, float* __restrict__ out)
{
    __shared__ float lvl_s[5], lvl_m[5];
    __shared__ float red[2][4];
    const int nb[5] = {2048, 512, 128, 32, 16};
    const int off[5] = {0, 2048, 2560, 2688, 2720};
    const float npix[5] = {16.f * 512 * 512, 16.f * 256 * 256, 16.f * 128 * 128,
                           16.f * 64 * 64, 16.f * 32 * 32};
    const int tid = threadIdx.x;

    for (int l = 0; l < 5; ++l) {
        float s = 0.f, m = 0.f;
        for (int i = tid; i < nb[l]; i += 256) {
            s += partials[2 * (off[l] + i)];
            m += partials[2 * (off[l] + i) + 1];
        }
#pragma unroll
        for (int o = 32; o > 0; o >>= 1) {
            s += __shfl_down(s, o);
            m += __shfl_down(m, o);
        }
        int wave = tid >> 6, lane = tid & 63;
        if (lane == 0) { red[0][wave] = s; red[1][wave] = m; }
        __syncthreads();
        if (tid == 0) {
            lvl_s[l] = (red[0][0] + red[0][1] + red[0][2] + red[0][3]) / npix[l];
            lvl_m[l] = (red[1][0] + red[1][1] + red[1][2] + red[1][3]) / npix[l];
        }
        __syncthreads();
    }

    if (tid == 0) {
        const float w[5] = {0.0448f, 0.2856f, 0.3001f, 0.2363f, 0.1333f};
        float v = powf(lvl_m[0], w[0]) * powf(lvl_m[1], w[1]) * powf(lvl_m[2], w[2]) *
                  powf(lvl_m[3], w[3]) * powf(lvl_s[4], w[4]);
        v *= 0.5f;
        v = fminf(fmaxf(v, 0.f), 1.f);
        out[0] = v;
    }
}

extern "C" void kernel_launch(void* const* d_in, const int* in_sizes, int n_in,
                              void* d_out, int out_size, void* d_ws, size_t ws_size,
                              hipStream_t stream) {
    const float* img1 = (const float*)d_in[0];
    const float* img2 = (const float*)d_in[1];
    float* out = (float*)d_out;

    const int B = 16;

    float* wsf = (float*)d_ws;
    float* partials = wsf;
    float* p = wsf + 5472;
    float* l1a = p; p += (size_t)B * 256 * 256;
    float* l1b = p; p += (size_t)B * 256 * 256;
    float* l2a = p; p += (size_t)B * 128 * 128;
    float* l2b = p; p += (size_t)B * 128 * 128;
    float* l3a = p; p += (size_t)B * 64 * 64;
    float* l3b = p; p += (size_t)B * 64 * 64;
    float* l4a = p; p += (size_t)B * 32 * 32;
    float* l4b = p; p += (size_t)B * 32 * 32;

    dim3 block(256);

    ssim_l0_pool_kernel<<<dim3(8, 16, B), block, 0, stream>>>(
        img1, img2, l1a, l1b, l2a, l2b, l3a, l3b, l4a, l4b, partials);

    ssim_rest_kernel<<<dim3(688), block, 0, stream>>>(
        l1a, l1b, l2a, l2b, l3a, l3b, l4a, l4b, partials + 2 * 2048);

    finalize_kernel<<<1, block, 0, stream>>>(partials, out);
}